// Round 15
// baseline (261.693 us; speedup 1.0000x reference)
//
#include <hip/hip_runtime.h>
#include <cstddef>
#include <cstdint>

#define NB 4
#define ND 512
#define NT 4096
#define NK 4096
#define NBT (NB * NT)
#define BKR 32         // real-k chunk
#define NCH (ND / BKR) // 16 chunks
#define CT (NK / 256)  // 16 col-blocks

typedef __attribute__((ext_vector_type(4))) float f32x4;
typedef __attribute__((ext_vector_type(8))) short short8;
typedef __attribute__((ext_vector_type(8))) unsigned short u16x8;
typedef unsigned short u16;

__device__ inline u16 f2bf_rn(float f) {
  unsigned u = __float_as_uint(f);
  return (u16)((u + 0x7FFFu + ((u >> 16) & 1u)) >> 16);
}
__device__ inline float bf2f(u16 h) {
  return __uint_as_float(((unsigned)h) << 16);
}
__device__ inline void gload16(void* lds_p, const void* g) {
  __builtin_amdgcn_global_load_lds(
      (const __attribute__((address_space(1))) unsigned int*)g,
      (__attribute__((address_space(3))) unsigned int*)lds_p, 16, 0, 0);
}

// ---------------------------------------------------- e conversion + norm --
__global__ void conv_e_kernel(const float* __restrict__ emb,
                              u16* __restrict__ eh2,
                              float* __restrict__ enorm) {
  int row = blockIdx.x * 4 + (threadIdx.x >> 6);
  int l = threadIdx.x & 63;
  const float* e = emb + (size_t)row * ND;
  float s = 0.f;
#pragma unroll
  for (int i = 0; i < ND / 64; ++i) {
    int idx = l + i * 64;
    float v = e[idx];
    s += v * v;
    eh2[(size_t)row * ND + idx] = f2bf_rn(2.f * v);
  }
#pragma unroll
  for (int m = 32; m; m >>= 1) s += __shfl_xor(s, m);
  if (l == 0) enorm[row] = s;
}

// ------------------- x conversion (+ transpose) + sum(x^2) partials --------
__global__ __launch_bounds__(256) void conv_x_kernel(const float* __restrict__ x,
                                                     u16* __restrict__ xh,
                                                     float* __restrict__ xsq) {
  __shared__ float tile[64][68];
  const int tid = threadIdx.x;
  const int bt0 = blockIdx.x * 64, d0 = blockIdx.y * 64;
  const int b = bt0 / NT, t0 = bt0 % NT;
  const float* xb = x + (size_t)b * ND * NT;
  float s2 = 0.f;
  {
    const int tt4 = (tid & 15) * 4, ddb = tid >> 4;
#pragma unroll
    for (int p = 0; p < 4; ++p) {
      const int dd = ddb + p * 16;
      float4 v = *(const float4*)&xb[(size_t)(d0 + dd) * NT + t0 + tt4];
      s2 += v.x * v.x + v.y * v.y + v.z * v.z + v.w * v.w;
      *(float4*)&tile[dd][tt4] = v;
    }
  }
  __syncthreads();
  {
    const int t_loc = tid >> 2, dg = tid & 3;
    u16 hs[16];
#pragma unroll
    for (int j = 0; j < 16; ++j) hs[j] = f2bf_rn(tile[dg * 16 + j][t_loc]);
    const size_t base = (size_t)(bt0 + t_loc) * ND + d0 + dg * 16;
    *(u16x8*)&xh[base] = *(const u16x8*)&hs[0];
    *(u16x8*)&xh[base + 8] = *(const u16x8*)&hs[8];
  }
#pragma unroll
  for (int m = 32; m; m >>= 1) s2 += __shfl_xor(s2, m);
  __shared__ float wsum[4];
  if ((tid & 63) == 0) wsum[tid >> 6] = s2;
  __syncthreads();
  if (tid == 0)
    xsq[blockIdx.y * gridDim.x + blockIdx.x] =
        wsum[0] + wsum[1] + wsum[2] + wsum[3];
}

// ------------------- hi-only GEMM + per-block TOP-2 argmin -----------------
// Approx scores use ONLY xh*eh2 (1/3 the MFMA + LDS work of the 3-product
// split; approx error sigma ~0.15 vs typical top-2 gap ~9). Safety: keep
// TOP-2 per 256-col block (covers a same-block spoiler), exact top-4 rescore
// downstream. 256x256 tile, 16 waves of 64x64, BKR=32, TRIPLE-buffered LDS
// (96 KiB) -> staged loads get 2 chunks (~1800 cyc) of slack, counted VMC(2),
// raw barriers (never a full vmcnt drain in the main loop).
__device__ __forceinline__ void stage_op(
    u16 (&lds)[3][2][256][BKR], int bn, int op, int tn,
    const u16* __restrict__ src, int rowbase, int w, int l) {
  if (tn >= NCH) return;
  const int kA = tn * BKR;
  const int rowL = w * 16 + (l >> 2);  // 16 waves x 16 rows = 256 rows
  const int gslot = (l & 3) ^ ((rowL >> 1) & 3);  // pre-swizzled source
  gload16(&lds[bn][op][w * 16][0],
          &src[(size_t)(rowbase + rowL) * ND + kA + gslot * 8]);
}

__global__ __launch_bounds__(1024, 4) void argmin_gemm_kernel(
    const u16* __restrict__ xh, const u16* __restrict__ eh2,
    const float* __restrict__ enorm, float* __restrict__ cand_v,
    int* __restrict__ cand_i) {
  __shared__ u16 lds[3][2][256][BKR];  // [buf][aH,bH][row][k] = 96 KiB
  const int tid = threadIdx.x;
  const int w = tid >> 6, l = tid & 63;
  const int l15 = l & 15, l4 = l >> 4;
  const int wm = w >> 2, wn = w & 3;  // 4x4 wave grid, 64x64 each
  // XCD-aware bijective swizzle: nwg=1024, 128 blocks per XCD chunk.
  const int id = blockIdx.x;
  const int id_sw = (id & 7) * 128 + (id >> 3);
  const int bx = id_sw & 63, by = id_sw >> 6;
  const int bt0 = bx * 256, c0g = by * 256;

  f32x4 acc[4][2][2];  // [m][qn][n] = 64 regs
#pragma unroll
  for (int m = 0; m < 4; ++m)
#pragma unroll
    for (int qn = 0; qn < 2; ++qn)
#pragma unroll
      for (int n = 0; n < 2; ++n) acc[m][qn][n] = (f32x4)0.f;

#define SLOT(row) (((l4) ^ (((row) >> 1) & 3)) * 8)
#define DS_A(AF)                                                         \
  _Pragma("unroll") for (int m = 0; m < 4; ++m) {                        \
    const int row = wm * 64 + m * 16 + l15;                              \
    AF[m] = *(const short8*)&lds[cur][0][row][SLOT(row)];                \
  }
#define DS_B(BF)                                                         \
  _Pragma("unroll") for (int qn = 0; qn < 2; ++qn) {                     \
    _Pragma("unroll") for (int n = 0; n < 2; ++n) {                      \
      const int row = wn * 64 + qn * 32 + n * 16 + l15;                  \
      BF[qn * 2 + n] = *(const short8*)&lds[cur][1][row][SLOT(row)];     \
    }                                                                    \
  }
#define MM(AF, BF)                                                       \
  _Pragma("unroll") for (int m = 0; m < 4; ++m) {                        \
    _Pragma("unroll") for (int qn = 0; qn < 2; ++qn) {                   \
      _Pragma("unroll") for (int n = 0; n < 2; ++n) {                    \
        acc[m][qn][n] = __builtin_amdgcn_mfma_f32_16x16x32_bf16(         \
            AF[m], BF[qn * 2 + n], acc[m][qn][n], 0, 0, 0);              \
      }                                                                  \
    }                                                                    \
  }
#define BAR __builtin_amdgcn_s_barrier()
#define SB0 __builtin_amdgcn_sched_barrier(0)
#define VMC(N) asm volatile("s_waitcnt vmcnt(" #N ")" ::: "memory")

  // prologue: stage c0->buf0, c1->buf1; drain c0; entry Q=[c1 2].
  stage_op(lds, 0, 0, 0, xh, bt0, w, l);
  stage_op(lds, 0, 1, 0, eh2, c0g, w, l);
  stage_op(lds, 1, 0, 1, xh, bt0, w, l);
  stage_op(lds, 1, 1, 1, eh2, c0g, w, l);
  VMC(2);
  BAR;
  SB0;

  for (int t = 0; t < NCH; ++t) {
    const int cur = t % 3;
    const int b2 = (t + 2) % 3;
    // stage chunk t+2 (2-chunk prefetch slack; no-op past the end)
    stage_op(lds, b2, 0, t + 2, xh, bt0, w, l);
    stage_op(lds, b2, 1, t + 2, eh2, c0g, w, l);
    short8 aH[4], bH[4];
    DS_A(aH);
    DS_B(bH);
    MM(aH, bH);
    if (t < NCH - 2) {
      VMC(2);  // drain c(t+1); c(t+2) stays in flight one more chunk
    } else {
      VMC(0);
    }
    BAR;  // reads of cur complete (consumed by MFMAs) -> buf reuse safe
    SB0;
  }
#undef SLOT
#undef DS_A
#undef DS_B
#undef MM
#undef VMC

  // ---- epilogue: per-row TOP-2 over this block's 256 cols ----
  float en[2][2];
#pragma unroll
  for (int qn = 0; qn < 2; ++qn)
#pragma unroll
    for (int n = 0; n < 2; ++n)
      en[qn][n] = enorm[c0g + wn * 64 + qn * 32 + n * 16 + l15];

  float* cvs2 = (float*)&lds[0][0][0][0];    // [4][256][2]
  int* cis2 = (int*)(cvs2 + 4 * 256 * 2);    // [4][256][2]

#pragma unroll
  for (int m = 0; m < 4; ++m) {
#pragma unroll
    for (int q = 0; q < 4; ++q) {
      float v1 = INFINITY, v2 = INFINITY;
      int i1 = 0, i2 = 0;
#pragma unroll
      for (int qn = 0; qn < 2; ++qn)  // ascending col order
#pragma unroll
        for (int n = 0; n < 2; ++n) {
          const float s = en[qn][n] - acc[m][qn][n][q];
          const int c = c0g + wn * 64 + qn * 32 + n * 16 + l15;
          if (s < v1) {
            v2 = v1; i2 = i1; v1 = s; i1 = c;
          } else if (s < v2) {
            v2 = s; i2 = c;
          }
        }
#pragma unroll
      for (int msk = 1; msk < 16; msk <<= 1) {
        const float ov1 = __shfl_xor(v1, msk);
        const int oi1 = __shfl_xor(i1, msk);
        const float ov2 = __shfl_xor(v2, msk);
        const int oi2 = __shfl_xor(i2, msk);
        const bool tk = ov1 < v1 || (ov1 == v1 && oi1 < i1);
        const float w2 = tk ? ov2 : v2;
        const int wj2 = tk ? oi2 : i2;
        const float lo1 = tk ? v1 : ov1;
        const int lj1 = tk ? i1 : oi1;
        v1 = tk ? ov1 : v1;
        i1 = tk ? oi1 : i1;
        const bool u = w2 < lo1 || (w2 == lo1 && wj2 < lj1);
        v2 = u ? w2 : lo1;
        i2 = u ? wj2 : lj1;
      }
      if (l15 == 0) {
        const int row = wm * 64 + m * 16 + l4 * 4 + q;
        cvs2[(wn * 256 + row) * 2 + 0] = v1;
        cis2[(wn * 256 + row) * 2 + 0] = i1;
        cvs2[(wn * 256 + row) * 2 + 1] = v2;
        cis2[(wn * 256 + row) * 2 + 1] = i2;
      }
    }
  }
  __syncthreads();
  if (tid < 256) {
    float v1 = INFINITY, v2 = INFINITY;
    int i1 = 0, i2 = 0;
#pragma unroll
    for (int g = 0; g < 4; ++g)
#pragma unroll
      for (int s = 0; s < 2; ++s) {
        const float v = cvs2[(g * 256 + tid) * 2 + s];
        const int i = cis2[(g * 256 + tid) * 2 + s];
        if (v < v1 || (v == v1 && i < i1)) {
          v2 = v1; i2 = i1; v1 = v; i1 = i;
        } else if (v < v2 || (v == v2 && i < i2)) {
          v2 = v; i2 = i;
        }
      }
    cand_v[(size_t)(by * 2 + 0) * NBT + bt0 + tid] = v1;
    cand_i[(size_t)(by * 2 + 0) * NBT + bt0 + tid] = i1;
    cand_v[(size_t)(by * 2 + 1) * NBT + bt0 + tid] = v2;
    cand_i[(size_t)(by * 2 + 1) * NBT + bt0 + tid] = i2;
  }
#undef BAR
#undef SB0
}

// -------- combine (32 cands) + exact fp32 top-4 rescore + loss partial -----
__global__ __launch_bounds__(256) void combine_rescore_kernel(
    const float* __restrict__ cand_v, const int* __restrict__ cand_i,
    const float* __restrict__ x, const float* __restrict__ emb,
    const float* __restrict__ enorm, int* __restrict__ idx_ws,
    float* __restrict__ idxf, float* __restrict__ lpart) {
  const int r = blockIdx.x * 256 + threadIdx.x;
  float v0 = INFINITY, v1 = INFINITY, v2 = INFINITY, v3 = INFINITY;
  int j0 = 0, j1 = 0, j2 = 0, j3 = 0;
#pragma unroll
  for (int c = 0; c < CT * 2; ++c) {
    const float v = cand_v[(size_t)c * NBT + r];
    const int i = cand_i[(size_t)c * NBT + r];
    if (v < v0 || (v == v0 && i < j0)) {
      v3 = v2; j3 = j2; v2 = v1; j2 = j1; v1 = v0; j1 = j0; v0 = v; j0 = i;
    } else if (v < v1 || (v == v1 && i < j1)) {
      v3 = v2; j3 = j2; v2 = v1; j2 = j1; v1 = v; j1 = i;
    } else if (v < v2 || (v == v2 && i < j2)) {
      v3 = v2; j3 = j2; v2 = v; j2 = i;
    } else if (v < v3 || (v == v3 && i < j3)) {
      v3 = v; j3 = i;
    }
  }
  const int b = r >> 12, t = r & (NT - 1);
  const float* xb = x + (size_t)b * ND * NT + t;
  const float* e0 = emb + (size_t)j0 * ND;
  const float* e1 = emb + (size_t)j1 * ND;
  const float* e2 = emb + (size_t)j2 * ND;
  const float* e3 = emb + (size_t)j3 * ND;
  float d0 = 0.f, d1 = 0.f, d2 = 0.f, d3 = 0.f;
#pragma unroll 4
  for (int d = 0; d < ND; ++d) {
    const float xv = xb[(size_t)d * NT];
    d0 += xv * e0[d];
    d1 += xv * e1[d];
    d2 += xv * e2[d];
    d3 += xv * e3[d];
  }
  const float s0 = enorm[j0] - 2.f * d0;
  const float s1 = enorm[j1] - 2.f * d1;
  const float s2 = enorm[j2] - 2.f * d2;
  const float s3 = enorm[j3] - 2.f * d3;
  float sb = s0;
  int best = j0;
  if (s1 < sb || (s1 == sb && j1 < best)) { sb = s1; best = j1; }
  if (s2 < sb || (s2 == sb && j2 < best)) { sb = s2; best = j2; }
  if (s3 < sb || (s3 == sb && j3 < best)) { sb = s3; best = j3; }
  idx_ws[r] = best;
  idxf[r] = (float)best;
  // per-row loss term: sum_d (x-v)^2 - sum_d x^2 = enorm[best] - 2*dot_best
  float lsum = sb;
#pragma unroll
  for (int m = 32; m; m >>= 1) lsum += __shfl_xor(lsum, m);
  __shared__ float wsum[4];
  if ((threadIdx.x & 63) == 0) wsum[threadIdx.x >> 6] = lsum;
  __syncthreads();
  if (threadIdx.x == 0)
    lpart[blockIdx.x] = wsum[0] + wsum[1] + wsum[2] + wsum[3];
}

// ----------------------------------------------- gather (emb -> [B,D,T]) ---
__global__ __launch_bounds__(256) void gather_kernel(
    const float* __restrict__ emb, const int* __restrict__ idx_ws,
    float* __restrict__ vals_out) {
  __shared__ float tile[64][65];
  const int tid = threadIdx.x;
  const int bt0 = blockIdx.x * 64;
  const int d0 = blockIdx.y * 64;
  const int b = bt0 / NT;
  const int t0 = bt0 % NT;
  {
    const int dd4 = (tid & 15) * 4;
    const int ttb = tid >> 4;
#pragma unroll
    for (int p = 0; p < 4; ++p) {
      const int tt = ttb + p * 16;
      const int r = idx_ws[bt0 + tt];
      float4 v = *(const float4*)&emb[(size_t)r * ND + d0 + dd4];
      tile[tt][dd4 + 0] = v.x;
      tile[tt][dd4 + 1] = v.y;
      tile[tt][dd4 + 2] = v.z;
      tile[tt][dd4 + 3] = v.w;
    }
  }
  __syncthreads();
  {
    const int tt4 = (tid & 15) * 4;
    const int ddb = tid >> 4;
#pragma unroll
    for (int p = 0; p < 4; ++p) {
      const int dd = ddb + p * 16;
      float4 v;
      v.x = tile[tt4 + 0][dd];
      v.y = tile[tt4 + 1][dd];
      v.z = tile[tt4 + 2][dd];
      v.w = tile[tt4 + 3][dd];
      const size_t o = (size_t)b * ND * NT + (size_t)(d0 + dd) * NT + t0 + tt4;
      *(float4*)&vals_out[o] = v;
    }
  }
}

// ----------------------------------------------------------------- loss ----
__global__ void loss_kernel(const float* __restrict__ partials, int n,
                            float* __restrict__ out) {
  float s = 0.f;
  for (int i = threadIdx.x; i < n; i += 256) s += partials[i];
#pragma unroll
  for (int m = 32; m; m >>= 1) s += __shfl_xor(s, m);
  __shared__ float wsum[4];
  if ((threadIdx.x & 63) == 0) wsum[threadIdx.x >> 6] = s;
  __syncthreads();
  if (threadIdx.x == 0)
    out[0] = 2.0f * (wsum[0] + wsum[1] + wsum[2] + wsum[3]) /
             (float)((size_t)NB * ND * NT);
}

// --------------------------------------------------------------- launch ----
extern "C" void kernel_launch(void* const* d_in, const int* in_sizes, int n_in,
                              void* d_out, int out_size, void* d_ws,
                              size_t ws_size, hipStream_t stream) {
  const float* x = (const float*)d_in[0];
  const float* emb = (const float*)d_in[1];
  float* out = (float*)d_out;
  float* vals_out = out;                         // [B, D, T]
  float* idxf_out = out + (size_t)NB * ND * NT;  // [B, T] as float
  float* loss_out = idxf_out + NBT;              // scalar

  u16* xh = (u16*)d_ws;                            // NBT*ND
  u16* eh2 = xh + (size_t)NBT * ND;                // NK*ND
  float* enorm = (float*)(eh2 + (size_t)NK * ND);  // NK
  float* cand_v = enorm + NK;                      // CT*2*NBT
  int* cand_i = (int*)(cand_v + (size_t)CT * 2 * NBT);
  int* idx_ws = cand_i + (size_t)CT * 2 * NBT;  // NBT
  float* partials = (float*)(idx_ws + NBT);     // 2048 (x^2) + 64 (rescore)

  conv_e_kernel<<<NK / 4, 256, 0, stream>>>(emb, eh2, enorm);
  conv_x_kernel<<<dim3(NBT / 64, ND / 64), 256, 0, stream>>>(x, xh, partials);
  argmin_gemm_kernel<<<1024, 1024, 0, stream>>>(xh, eh2, enorm, cand_v,
                                                cand_i);
  combine_rescore_kernel<<<NBT / 256, 256, 0, stream>>>(
      cand_v, cand_i, x, emb, enorm, idx_ws, idxf_out, partials + 2048);
  gather_kernel<<<dim3(NBT / 64, ND / 64), 256, 0, stream>>>(emb, idx_ws,
                                                             vals_out);
  loss_kernel<<<1, 256, 0, stream>>>(partials, 2048 + 64, loss_out);
}

// Round 16
// 209.232 us; speedup vs baseline: 1.2507x; 1.2507x over previous
//
#include <hip/hip_runtime.h>
#include <cstddef>
#include <cstdint>

#define NB 4
#define ND 512
#define NT 4096
#define NK 4096
#define NBT (NB * NT)
#define BKR 32         // real-k chunk
#define NCH (ND / BKR) // 16 chunks
#define CT (NK / 256)  // 16 col-blocks

typedef __attribute__((ext_vector_type(4))) float f32x4;
typedef __attribute__((ext_vector_type(8))) short short8;
typedef __attribute__((ext_vector_type(8))) unsigned short u16x8;
typedef unsigned short u16;

__device__ inline u16 f2bf_rn(float f) {
  unsigned u = __float_as_uint(f);
  return (u16)((u + 0x7FFFu + ((u >> 16) & 1u)) >> 16);
}
__device__ inline float bf2f(u16 h) {
  return __uint_as_float(((unsigned)h) << 16);
}
__device__ inline void gload16(void* lds_p, const void* g) {
  __builtin_amdgcn_global_load_lds(
      (const __attribute__((address_space(1))) unsigned int*)g,
      (__attribute__((address_space(3))) unsigned int*)lds_p, 16, 0, 0);
}

// ---------------------------------------------------- e conversion + norm --
__global__ void conv_e_kernel(const float* __restrict__ emb,
                              u16* __restrict__ eh2,
                              float* __restrict__ enorm) {
  int row = blockIdx.x * 4 + (threadIdx.x >> 6);
  int l = threadIdx.x & 63;
  const float* e = emb + (size_t)row * ND;
  float s = 0.f;
#pragma unroll
  for (int i = 0; i < ND / 64; ++i) {
    int idx = l + i * 64;
    float v = e[idx];
    s += v * v;
    eh2[(size_t)row * ND + idx] = f2bf_rn(2.f * v);
  }
#pragma unroll
  for (int m = 32; m; m >>= 1) s += __shfl_xor(s, m);
  if (l == 0) enorm[row] = s;
}

// ------------------- x conversion (+ transpose) + sum(x^2) partials --------
__global__ __launch_bounds__(256) void conv_x_kernel(const float* __restrict__ x,
                                                     u16* __restrict__ xh,
                                                     float* __restrict__ xsq) {
  __shared__ float tile[64][68];
  const int tid = threadIdx.x;
  const int bt0 = blockIdx.x * 64, d0 = blockIdx.y * 64;
  const int b = bt0 / NT, t0 = bt0 % NT;
  const float* xb = x + (size_t)b * ND * NT;
  float s2 = 0.f;
  {
    const int tt4 = (tid & 15) * 4, ddb = tid >> 4;
#pragma unroll
    for (int p = 0; p < 4; ++p) {
      const int dd = ddb + p * 16;
      float4 v = *(const float4*)&xb[(size_t)(d0 + dd) * NT + t0 + tt4];
      s2 += v.x * v.x + v.y * v.y + v.z * v.z + v.w * v.w;
      *(float4*)&tile[dd][tt4] = v;
    }
  }
  __syncthreads();
  {
    const int t_loc = tid >> 2, dg = tid & 3;
    u16 hs[16];
#pragma unroll
    for (int j = 0; j < 16; ++j) hs[j] = f2bf_rn(tile[dg * 16 + j][t_loc]);
    const size_t base = (size_t)(bt0 + t_loc) * ND + d0 + dg * 16;
    *(u16x8*)&xh[base] = *(const u16x8*)&hs[0];
    *(u16x8*)&xh[base + 8] = *(const u16x8*)&hs[8];
  }
#pragma unroll
  for (int m = 32; m; m >>= 1) s2 += __shfl_xor(s2, m);
  __shared__ float wsum[4];
  if ((tid & 63) == 0) wsum[tid >> 6] = s2;
  __syncthreads();
  if (tid == 0)
    xsq[blockIdx.y * gridDim.x + blockIdx.x] =
        wsum[0] + wsum[1] + wsum[2] + wsum[3];
}

// ------------------- hi-only GEMM + per-block TOP-2 argmin -----------------
// (unchanged from r15 — validated, GEMM no longer the bottleneck)
__device__ __forceinline__ void stage_op(
    u16 (&lds)[3][2][256][BKR], int bn, int op, int tn,
    const u16* __restrict__ src, int rowbase, int w, int l) {
  if (tn >= NCH) return;
  const int kA = tn * BKR;
  const int rowL = w * 16 + (l >> 2);  // 16 waves x 16 rows = 256 rows
  const int gslot = (l & 3) ^ ((rowL >> 1) & 3);  // pre-swizzled source
  gload16(&lds[bn][op][w * 16][0],
          &src[(size_t)(rowbase + rowL) * ND + kA + gslot * 8]);
}

__global__ __launch_bounds__(1024, 4) void argmin_gemm_kernel(
    const u16* __restrict__ xh, const u16* __restrict__ eh2,
    const float* __restrict__ enorm, float* __restrict__ cand_v,
    int* __restrict__ cand_i) {
  __shared__ u16 lds[3][2][256][BKR];  // [buf][aH,bH][row][k] = 96 KiB
  const int tid = threadIdx.x;
  const int w = tid >> 6, l = tid & 63;
  const int l15 = l & 15, l4 = l >> 4;
  const int wm = w >> 2, wn = w & 3;  // 4x4 wave grid, 64x64 each
  const int id = blockIdx.x;
  const int id_sw = (id & 7) * 128 + (id >> 3);
  const int bx = id_sw & 63, by = id_sw >> 6;
  const int bt0 = bx * 256, c0g = by * 256;

  f32x4 acc[4][2][2];  // [m][qn][n] = 64 regs
#pragma unroll
  for (int m = 0; m < 4; ++m)
#pragma unroll
    for (int qn = 0; qn < 2; ++qn)
#pragma unroll
      for (int n = 0; n < 2; ++n) acc[m][qn][n] = (f32x4)0.f;

#define SLOT(row) (((l4) ^ (((row) >> 1) & 3)) * 8)
#define DS_A(AF)                                                         \
  _Pragma("unroll") for (int m = 0; m < 4; ++m) {                        \
    const int row = wm * 64 + m * 16 + l15;                              \
    AF[m] = *(const short8*)&lds[cur][0][row][SLOT(row)];                \
  }
#define DS_B(BF)                                                         \
  _Pragma("unroll") for (int qn = 0; qn < 2; ++qn) {                     \
    _Pragma("unroll") for (int n = 0; n < 2; ++n) {                      \
      const int row = wn * 64 + qn * 32 + n * 16 + l15;                  \
      BF[qn * 2 + n] = *(const short8*)&lds[cur][1][row][SLOT(row)];     \
    }                                                                    \
  }
#define MM(AF, BF)                                                       \
  _Pragma("unroll") for (int m = 0; m < 4; ++m) {                        \
    _Pragma("unroll") for (int qn = 0; qn < 2; ++qn) {                   \
      _Pragma("unroll") for (int n = 0; n < 2; ++n) {                    \
        acc[m][qn][n] = __builtin_amdgcn_mfma_f32_16x16x32_bf16(         \
            AF[m], BF[qn * 2 + n], acc[m][qn][n], 0, 0, 0);              \
      }                                                                  \
    }                                                                    \
  }
#define BAR __builtin_amdgcn_s_barrier()
#define SB0 __builtin_amdgcn_sched_barrier(0)
#define VMC(N) asm volatile("s_waitcnt vmcnt(" #N ")" ::: "memory")

  stage_op(lds, 0, 0, 0, xh, bt0, w, l);
  stage_op(lds, 0, 1, 0, eh2, c0g, w, l);
  stage_op(lds, 1, 0, 1, xh, bt0, w, l);
  stage_op(lds, 1, 1, 1, eh2, c0g, w, l);
  VMC(2);
  BAR;
  SB0;

  for (int t = 0; t < NCH; ++t) {
    const int cur = t % 3;
    const int b2 = (t + 2) % 3;
    stage_op(lds, b2, 0, t + 2, xh, bt0, w, l);
    stage_op(lds, b2, 1, t + 2, eh2, c0g, w, l);
    short8 aH[4], bH[4];
    DS_A(aH);
    DS_B(bH);
    MM(aH, bH);
    if (t < NCH - 2) {
      VMC(2);
    } else {
      VMC(0);
    }
    BAR;
    SB0;
  }
#undef SLOT
#undef DS_A
#undef DS_B
#undef MM
#undef VMC

  // ---- epilogue: per-row TOP-2 over this block's 256 cols ----
  float en[2][2];
#pragma unroll
  for (int qn = 0; qn < 2; ++qn)
#pragma unroll
    for (int n = 0; n < 2; ++n)
      en[qn][n] = enorm[c0g + wn * 64 + qn * 32 + n * 16 + l15];

  float* cvs2 = (float*)&lds[0][0][0][0];    // [4][256][2]
  int* cis2 = (int*)(cvs2 + 4 * 256 * 2);    // [4][256][2]

#pragma unroll
  for (int m = 0; m < 4; ++m) {
#pragma unroll
    for (int q = 0; q < 4; ++q) {
      float v1 = INFINITY, v2 = INFINITY;
      int i1 = 0, i2 = 0;
#pragma unroll
      for (int qn = 0; qn < 2; ++qn)  // ascending col order
#pragma unroll
        for (int n = 0; n < 2; ++n) {
          const float s = en[qn][n] - acc[m][qn][n][q];
          const int c = c0g + wn * 64 + qn * 32 + n * 16 + l15;
          if (s < v1) {
            v2 = v1; i2 = i1; v1 = s; i1 = c;
          } else if (s < v2) {
            v2 = s; i2 = c;
          }
        }
#pragma unroll
      for (int msk = 1; msk < 16; msk <<= 1) {
        const float ov1 = __shfl_xor(v1, msk);
        const int oi1 = __shfl_xor(i1, msk);
        const float ov2 = __shfl_xor(v2, msk);
        const int oi2 = __shfl_xor(i2, msk);
        const bool tk = ov1 < v1 || (ov1 == v1 && oi1 < i1);
        const float w2 = tk ? ov2 : v2;
        const int wj2 = tk ? oi2 : i2;
        const float lo1 = tk ? v1 : ov1;
        const int lj1 = tk ? i1 : oi1;
        v1 = tk ? ov1 : v1;
        i1 = tk ? oi1 : i1;
        const bool u = w2 < lo1 || (w2 == lo1 && wj2 < lj1);
        v2 = u ? w2 : lo1;
        i2 = u ? wj2 : lj1;
      }
      if (l15 == 0) {
        const int row = wm * 64 + m * 16 + l4 * 4 + q;
        cvs2[(wn * 256 + row) * 2 + 0] = v1;
        cis2[(wn * 256 + row) * 2 + 0] = i1;
        cvs2[(wn * 256 + row) * 2 + 1] = v2;
        cis2[(wn * 256 + row) * 2 + 1] = i2;
      }
    }
  }
  __syncthreads();
  if (tid < 256) {
    float v1 = INFINITY, v2 = INFINITY;
    int i1 = 0, i2 = 0;
#pragma unroll
    for (int g = 0; g < 4; ++g)
#pragma unroll
      for (int s = 0; s < 2; ++s) {
        const float v = cvs2[(g * 256 + tid) * 2 + s];
        const int i = cis2[(g * 256 + tid) * 2 + s];
        if (v < v1 || (v == v1 && i < i1)) {
          v2 = v1; i2 = i1; v1 = v; i1 = i;
        } else if (v < v2 || (v == v2 && i < i2)) {
          v2 = v; i2 = i;
        }
      }
    cand_v[(size_t)(by * 2 + 0) * NBT + bt0 + tid] = v1;
    cand_i[(size_t)(by * 2 + 0) * NBT + bt0 + tid] = i1;
    cand_v[(size_t)(by * 2 + 1) * NBT + bt0 + tid] = v2;
    cand_i[(size_t)(by * 2 + 1) * NBT + bt0 + tid] = i2;
  }
#undef BAR
#undef SB0
}

// -------- wave-per-row combine + exact fp32 top-4 rescore + loss partial ---
// One 64-lane wave per output row (4 rows / 256-thread block, 4096 blocks):
// lanes 0-31 hold the 32 candidates; 4 butterfly-min passes (index tiebreak,
// unique indices -> clean elimination) give the approx top-4. Each lane then
// loads its 8 x values ONCE (d = l+64*i), reuses them for 4 candidate dots
// (e-row reads lane-coalesced), shuffle-reduces, and lane 0 picks the exact
// argmin with min-index tiebreak (identical semantics to the serial r15).
__global__ __launch_bounds__(256) void combine_rescore_kernel(
    const float* __restrict__ cand_v, const int* __restrict__ cand_i,
    const float* __restrict__ x, const float* __restrict__ emb,
    const float* __restrict__ enorm, int* __restrict__ idx_ws,
    float* __restrict__ idxf, float* __restrict__ lpart) {
  const int tid = threadIdx.x;
  const int wv = tid >> 6, l = tid & 63;
  const int r = blockIdx.x * 4 + wv;
  // ---- approx top-4 of 32 candidates (wave-parallel) ----
  float v = (l < 32) ? cand_v[(size_t)l * NBT + r] : INFINITY;
  int i = (l < 32) ? cand_i[(size_t)l * NBT + r] : 0x7fffffff;
  float mv[4];
  int mi[4];
#pragma unroll
  for (int k = 0; k < 4; ++k) {
    float bv = v;
    int bi = i;
#pragma unroll
    for (int msk = 1; msk < 64; msk <<= 1) {
      const float ov = __shfl_xor(bv, msk);
      const int oi = __shfl_xor(bi, msk);
      if (ov < bv || (ov == bv && oi < bi)) {
        bv = ov;
        bi = oi;
      }
    }
    mv[k] = bv;
    mi[k] = bi;
    if (i == bi) v = INFINITY;  // eliminate winner (indices unique)
  }
  // ---- exact fp32 dots: x loaded once per lane, 4 coalesced e-rows ----
  const int b = r >> 12, t = r & (NT - 1);
  const float* xb = x + (size_t)b * ND * NT + t;
  float xv[8];
#pragma unroll
  for (int ii = 0; ii < 8; ++ii) xv[ii] = xb[(size_t)(l + 64 * ii) * NT];
  float dot[4];
#pragma unroll
  for (int k = 0; k < 4; ++k) {
    const float* e = emb + (size_t)mi[k] * ND;
    float d = 0.f;
#pragma unroll
    for (int ii = 0; ii < 8; ++ii) d += xv[ii] * e[l + 64 * ii];
    dot[k] = d;
  }
#pragma unroll
  for (int msk = 1; msk < 64; msk <<= 1) {
#pragma unroll
    for (int k = 0; k < 4; ++k) dot[k] += __shfl_xor(dot[k], msk);
  }
  __shared__ float wsum[4];
  if (l == 0) {
    float sb = INFINITY;
    int best = 0x7fffffff;
#pragma unroll
    for (int k = 0; k < 4; ++k) {
      const float s = enorm[mi[k]] - 2.f * dot[k];
      if (s < sb || (s == sb && mi[k] < best)) {
        sb = s;
        best = mi[k];
      }
    }
    idx_ws[r] = best;
    idxf[r] = (float)best;
    wsum[wv] = sb;  // loss term: enorm[best] - 2*dot_best
  }
  __syncthreads();
  if (tid == 0)
    lpart[blockIdx.x] = wsum[0] + wsum[1] + wsum[2] + wsum[3];
}

// ----------------------------------------------- gather (emb -> [B,D,T]) ---
__global__ __launch_bounds__(256) void gather_kernel(
    const float* __restrict__ emb, const int* __restrict__ idx_ws,
    float* __restrict__ vals_out) {
  __shared__ float tile[64][65];
  const int tid = threadIdx.x;
  const int bt0 = blockIdx.x * 64;
  const int d0 = blockIdx.y * 64;
  const int b = bt0 / NT;
  const int t0 = bt0 % NT;
  {
    const int dd4 = (tid & 15) * 4;
    const int ttb = tid >> 4;
#pragma unroll
    for (int p = 0; p < 4; ++p) {
      const int tt = ttb + p * 16;
      const int r = idx_ws[bt0 + tt];
      float4 v = *(const float4*)&emb[(size_t)r * ND + d0 + dd4];
      tile[tt][dd4 + 0] = v.x;
      tile[tt][dd4 + 1] = v.y;
      tile[tt][dd4 + 2] = v.z;
      tile[tt][dd4 + 3] = v.w;
    }
  }
  __syncthreads();
  {
    const int tt4 = (tid & 15) * 4;
    const int ddb = tid >> 4;
#pragma unroll
    for (int p = 0; p < 4; ++p) {
      const int dd = ddb + p * 16;
      float4 v;
      v.x = tile[tt4 + 0][dd];
      v.y = tile[tt4 + 1][dd];
      v.z = tile[tt4 + 2][dd];
      v.w = tile[tt4 + 3][dd];
      const size_t o = (size_t)b * ND * NT + (size_t)(d0 + dd) * NT + t0 + tt4;
      *(float4*)&vals_out[o] = v;
    }
  }
}

// ----------------------------------------------------------------- loss ----
__global__ void loss_kernel(const float* __restrict__ partials, int n,
                            float* __restrict__ out) {
  float s = 0.f;
  for (int i = threadIdx.x; i < n; i += 256) s += partials[i];
#pragma unroll
  for (int m = 32; m; m >>= 1) s += __shfl_xor(s, m);
  __shared__ float wsum[4];
  if ((threadIdx.x & 63) == 0) wsum[threadIdx.x >> 6] = s;
  __syncthreads();
  if (threadIdx.x == 0)
    out[0] = 2.0f * (wsum[0] + wsum[1] + wsum[2] + wsum[3]) /
             (float)((size_t)NB * ND * NT);
}

// --------------------------------------------------------------- launch ----
extern "C" void kernel_launch(void* const* d_in, const int* in_sizes, int n_in,
                              void* d_out, int out_size, void* d_ws,
                              size_t ws_size, hipStream_t stream) {
  const float* x = (const float*)d_in[0];
  const float* emb = (const float*)d_in[1];
  float* out = (float*)d_out;
  float* vals_out = out;                         // [B, D, T]
  float* idxf_out = out + (size_t)NB * ND * NT;  // [B, T] as float
  float* loss_out = idxf_out + NBT;              // scalar

  u16* xh = (u16*)d_ws;                            // NBT*ND
  u16* eh2 = xh + (size_t)NBT * ND;                // NK*ND
  float* enorm = (float*)(eh2 + (size_t)NK * ND);  // NK
  float* cand_v = enorm + NK;                      // CT*2*NBT
  int* cand_i = (int*)(cand_v + (size_t)CT * 2 * NBT);
  int* idx_ws = cand_i + (size_t)CT * 2 * NBT;  // NBT
  float* partials = (float*)(idx_ws + NBT);     // 2048 (x^2) + 4096 (rescore)

  conv_e_kernel<<<NK / 4, 256, 0, stream>>>(emb, eh2, enorm);
  conv_x_kernel<<<dim3(NBT / 64, ND / 64), 256, 0, stream>>>(x, xh, partials);
  argmin_gemm_kernel<<<1024, 1024, 0, stream>>>(xh, eh2, enorm, cand_v,
                                                cand_i);
  combine_rescore_kernel<<<NBT / 4, 256, 0, stream>>>(
      cand_v, cand_i, x, emb, enorm, idx_ws, idxf_out, partials + 2048);
  gather_kernel<<<dim3(NBT / 64, ND / 64), 256, 0, stream>>>(emb, idx_ws,
                                                             vals_out);
  loss_kernel<<<1, 256, 0, stream>>>(partials, 2048 + 4096, loss_out);
}

// Round 17
// 207.176 us; speedup vs baseline: 1.2631x; 1.0099x over previous
//
#include <hip/hip_runtime.h>
#include <cstddef>
#include <cstdint>

#define NB 4
#define ND 512
#define NT 4096
#define NK 4096
#define NBT (NB * NT)
#define BKR 32         // real-k chunk
#define NCH (ND / BKR) // 16 chunks
#define CT (NK / 256)  // 16 col-blocks

typedef __attribute__((ext_vector_type(4))) float f32x4;
typedef __attribute__((ext_vector_type(8))) short short8;
typedef __attribute__((ext_vector_type(8))) unsigned short u16x8;
typedef unsigned short u16;

__device__ inline u16 f2bf_rn(float f) {
  unsigned u = __float_as_uint(f);
  return (u16)((u + 0x7FFFu + ((u >> 16) & 1u)) >> 16);
}
__device__ inline float bf2f(u16 h) {
  return __uint_as_float(((unsigned)h) << 16);
}
__device__ inline void gload16(void* lds_p, const void* g) {
  __builtin_amdgcn_global_load_lds(
      (const __attribute__((address_space(1))) unsigned int*)g,
      (__attribute__((address_space(3))) unsigned int*)lds_p, 16, 0, 0);
}

// ---------------------------------------------------- e conversion + norm --
__global__ void conv_e_kernel(const float* __restrict__ emb,
                              u16* __restrict__ eh2,
                              float* __restrict__ enorm) {
  int row = blockIdx.x * 4 + (threadIdx.x >> 6);
  int l = threadIdx.x & 63;
  const float* e = emb + (size_t)row * ND;
  float s = 0.f;
#pragma unroll
  for (int i = 0; i < ND / 64; ++i) {
    int idx = l + i * 64;
    float v = e[idx];
    s += v * v;
    eh2[(size_t)row * ND + idx] = f2bf_rn(2.f * v);
  }
#pragma unroll
  for (int m = 32; m; m >>= 1) s += __shfl_xor(s, m);
  if (l == 0) enorm[row] = s;
}

// ------------------- x conversion (+ transpose) + sum(x^2) partials --------
__global__ __launch_bounds__(256) void conv_x_kernel(const float* __restrict__ x,
                                                     u16* __restrict__ xh,
                                                     float* __restrict__ xsq) {
  __shared__ float tile[64][68];
  const int tid = threadIdx.x;
  const int bt0 = blockIdx.x * 64, d0 = blockIdx.y * 64;
  const int b = bt0 / NT, t0 = bt0 % NT;
  const float* xb = x + (size_t)b * ND * NT;
  float s2 = 0.f;
  {
    const int tt4 = (tid & 15) * 4, ddb = tid >> 4;
#pragma unroll
    for (int p = 0; p < 4; ++p) {
      const int dd = ddb + p * 16;
      float4 v = *(const float4*)&xb[(size_t)(d0 + dd) * NT + t0 + tt4];
      s2 += v.x * v.x + v.y * v.y + v.z * v.z + v.w * v.w;
      *(float4*)&tile[dd][tt4] = v;
    }
  }
  __syncthreads();
  {
    const int t_loc = tid >> 2, dg = tid & 3;
    u16 hs[16];
#pragma unroll
    for (int j = 0; j < 16; ++j) hs[j] = f2bf_rn(tile[dg * 16 + j][t_loc]);
    const size_t base = (size_t)(bt0 + t_loc) * ND + d0 + dg * 16;
    *(u16x8*)&xh[base] = *(const u16x8*)&hs[0];
    *(u16x8*)&xh[base + 8] = *(const u16x8*)&hs[8];
  }
#pragma unroll
  for (int m = 32; m; m >>= 1) s2 += __shfl_xor(s2, m);
  __shared__ float wsum[4];
  if ((tid & 63) == 0) wsum[tid >> 6] = s2;
  __syncthreads();
  if (tid == 0)
    xsq[blockIdx.y * gridDim.x + blockIdx.x] =
        wsum[0] + wsum[1] + wsum[2] + wsum[3];
}

// ------------- hi-only GEMM (128x256, 8 waves, 2 blocks/CU) + top-2 -------
// BM=128 x BN=256, 8 waves (2M x 4N) of 64x64 -> 128 regs/wave total, LDS
// 72 KiB (triple-buffered 24 KB chunks) => TWO blocks co-resident per CU
// (144 KiB LDS, 16 waves at the 128-reg cap). Independent barrier domains
// overlap one block's LDS-read/epilogue phases with the other's MFMA bursts
// — the cross-block pipelining intra-block scheduling couldn't provide.
// 3 staged loads/wave/chunk; counted VMC(3); never a full drain mid-loop.
__device__ __forceinline__ void stage_a(u16 (&la)[3][128][BKR], int bn, int tn,
                                        const u16* __restrict__ src,
                                        int rowbase, int w, int l) {
  if (tn >= NCH) return;
  const int kA = tn * BKR;
  const int rowL = w * 16 + (l >> 2);  // 8 waves x 16 rows = 128 rows
  const int gslot = (l & 3) ^ ((rowL >> 1) & 3);
  gload16(&la[bn][w * 16][0],
          &src[(size_t)(rowbase + rowL) * ND + kA + gslot * 8]);
}
__device__ __forceinline__ void stage_b(u16 (&lb)[3][256][BKR], int bn, int tn,
                                        const u16* __restrict__ src,
                                        int rowbase, int w, int l) {
  if (tn >= NCH) return;
  const int kA = tn * BKR;
#pragma unroll
  for (int i = 0; i < 2; ++i) {
    const int rowL = i * 128 + w * 16 + (l >> 2);
    const int gslot = (l & 3) ^ ((rowL >> 1) & 3);
    gload16(&lb[bn][i * 128 + w * 16][0],
            &src[(size_t)(rowbase + rowL) * ND + kA + gslot * 8]);
  }
}

__global__ __launch_bounds__(512, 4) void argmin_gemm_kernel(
    const u16* __restrict__ xh, const u16* __restrict__ eh2,
    const float* __restrict__ enorm, float* __restrict__ cand_v,
    int* __restrict__ cand_i) {
  __shared__ u16 lda[3][128][BKR];  // 24 KiB
  __shared__ u16 ldb[3][256][BKR];  // 48 KiB
  const int tid = threadIdx.x;
  const int w = tid >> 6, l = tid & 63;
  const int l15 = l & 15, l4 = l >> 4;
  const int wm = w >> 2, wn = w & 3;  // 2M x 4N waves, 64x64 each
  // XCD-aware bijective swizzle: nwg=2048, 256 blocks per XCD chunk.
  const int id = blockIdx.x;
  const int id_sw = (id & 7) * 256 + (id >> 3);
  const int bx = id_sw & 127, by = id_sw >> 7;
  const int bt0 = bx * 128, c0g = by * 256;

  f32x4 acc[4][2][2];  // [m][qn][n] = 64 regs
#pragma unroll
  for (int m = 0; m < 4; ++m)
#pragma unroll
    for (int qn = 0; qn < 2; ++qn)
#pragma unroll
      for (int n = 0; n < 2; ++n) acc[m][qn][n] = (f32x4)0.f;

#define SLOT(row) (((l4) ^ (((row) >> 1) & 3)) * 8)
#define DS_A(AF)                                                         \
  _Pragma("unroll") for (int m = 0; m < 4; ++m) {                        \
    const int row = wm * 64 + m * 16 + l15;                              \
    AF[m] = *(const short8*)&lda[cur][row][SLOT(row)];                   \
  }
#define DS_B(BF)                                                         \
  _Pragma("unroll") for (int qn = 0; qn < 2; ++qn) {                     \
    _Pragma("unroll") for (int n = 0; n < 2; ++n) {                      \
      const int row = wn * 64 + qn * 32 + n * 16 + l15;                  \
      BF[qn * 2 + n] = *(const short8*)&ldb[cur][row][SLOT(row)];        \
    }                                                                    \
  }
#define MM(AF, BF)                                                       \
  _Pragma("unroll") for (int m = 0; m < 4; ++m) {                        \
    _Pragma("unroll") for (int qn = 0; qn < 2; ++qn) {                   \
      _Pragma("unroll") for (int n = 0; n < 2; ++n) {                    \
        acc[m][qn][n] = __builtin_amdgcn_mfma_f32_16x16x32_bf16(         \
            AF[m], BF[qn * 2 + n], acc[m][qn][n], 0, 0, 0);              \
      }                                                                  \
    }                                                                    \
  }
#define BAR __builtin_amdgcn_s_barrier()
#define SB0 __builtin_amdgcn_sched_barrier(0)
#define VMC(N) asm volatile("s_waitcnt vmcnt(" #N ")" ::: "memory")

  // prologue: stage c0->buf0, c1->buf1 (6 loads); drain c0; Q=[c1:3].
  stage_a(lda, 0, 0, xh, bt0, w, l);
  stage_b(ldb, 0, 0, eh2, c0g, w, l);
  stage_a(lda, 1, 1, xh, bt0, w, l);
  stage_b(ldb, 1, 1, eh2, c0g, w, l);
  VMC(3);
  BAR;
  SB0;

#pragma unroll
  for (int t = 0; t < NCH; ++t) {
    const int cur = t % 3;
    const int b2 = (t + 2) % 3;
    // stage chunk t+2 (no-op past the end): Q = [c(t+1):3, c(t+2):3]
    stage_a(lda, b2, t + 2, xh, bt0, w, l);
    stage_b(ldb, b2, t + 2, eh2, c0g, w, l);
    short8 aH[4], bH[4];
    DS_A(aH);
    DS_B(bH);
    MM(aH, bH);
    if (t < NCH - 2) {
      VMC(3);  // drain c(t+1); c(t+2) keeps a full chunk of slack
    } else {
      VMC(0);
    }
    BAR;  // all waves' reads of cur done; c(t+1) landed everywhere
    SB0;
  }
#undef SLOT
#undef DS_A
#undef DS_B
#undef MM
#undef VMC

  // ---- epilogue: per-row TOP-2 over this block's 256 cols ----
  __syncthreads();  // LDS reuse below
  float en[2][2];
#pragma unroll
  for (int qn = 0; qn < 2; ++qn)
#pragma unroll
    for (int n = 0; n < 2; ++n)
      en[qn][n] = enorm[c0g + wn * 64 + qn * 32 + n * 16 + l15];

  float* cvs2 = (float*)&lda[0][0][0];     // [4][128][2]
  int* cis2 = (int*)(cvs2 + 4 * 128 * 2);  // [4][128][2]

#pragma unroll
  for (int m = 0; m < 4; ++m) {
#pragma unroll
    for (int q = 0; q < 4; ++q) {
      float v1 = INFINITY, v2 = INFINITY;
      int i1 = 0, i2 = 0;
#pragma unroll
      for (int qn = 0; qn < 2; ++qn)  // ascending col order
#pragma unroll
        for (int n = 0; n < 2; ++n) {
          const float s = en[qn][n] - acc[m][qn][n][q];
          const int c = c0g + wn * 64 + qn * 32 + n * 16 + l15;
          if (s < v1) {
            v2 = v1; i2 = i1; v1 = s; i1 = c;
          } else if (s < v2) {
            v2 = s; i2 = c;
          }
        }
#pragma unroll
      for (int msk = 1; msk < 16; msk <<= 1) {
        const float ov1 = __shfl_xor(v1, msk);
        const int oi1 = __shfl_xor(i1, msk);
        const float ov2 = __shfl_xor(v2, msk);
        const int oi2 = __shfl_xor(i2, msk);
        const bool tk = ov1 < v1 || (ov1 == v1 && oi1 < i1);
        const float w2 = tk ? ov2 : v2;
        const int wj2 = tk ? oi2 : i2;
        const float lo1 = tk ? v1 : ov1;
        const int lj1 = tk ? i1 : oi1;
        v1 = tk ? ov1 : v1;
        i1 = tk ? oi1 : i1;
        const bool u = w2 < lo1 || (w2 == lo1 && wj2 < lj1);
        v2 = u ? w2 : lo1;
        i2 = u ? wj2 : lj1;
      }
      if (l15 == 0) {
        const int row = wm * 64 + m * 16 + l4 * 4 + q;
        cvs2[(wn * 128 + row) * 2 + 0] = v1;
        cis2[(wn * 128 + row) * 2 + 0] = i1;
        cvs2[(wn * 128 + row) * 2 + 1] = v2;
        cis2[(wn * 128 + row) * 2 + 1] = i2;
      }
    }
  }
  __syncthreads();
  if (tid < 128) {
    float v1 = INFINITY, v2 = INFINITY;
    int i1 = 0, i2 = 0;
#pragma unroll
    for (int g = 0; g < 4; ++g)
#pragma unroll
      for (int s = 0; s < 2; ++s) {
        const float v = cvs2[(g * 128 + tid) * 2 + s];
        const int i = cis2[(g * 128 + tid) * 2 + s];
        if (v < v1 || (v == v1 && i < i1)) {
          v2 = v1; i2 = i1; v1 = v; i1 = i;
        } else if (v < v2 || (v == v2 && i < i2)) {
          v2 = v; i2 = i;
        }
      }
    cand_v[(size_t)(by * 2 + 0) * NBT + bt0 + tid] = v1;
    cand_i[(size_t)(by * 2 + 0) * NBT + bt0 + tid] = i1;
    cand_v[(size_t)(by * 2 + 1) * NBT + bt0 + tid] = v2;
    cand_i[(size_t)(by * 2 + 1) * NBT + bt0 + tid] = i2;
  }
#undef BAR
#undef SB0
}

// -------- wave-per-row combine + exact fp32 top-4 rescore + loss partial ---
__global__ __launch_bounds__(256) void combine_rescore_kernel(
    const float* __restrict__ cand_v, const int* __restrict__ cand_i,
    const float* __restrict__ x, const float* __restrict__ emb,
    const float* __restrict__ enorm, int* __restrict__ idx_ws,
    float* __restrict__ idxf, float* __restrict__ lpart) {
  const int tid = threadIdx.x;
  const int wv = tid >> 6, l = tid & 63;
  const int r = blockIdx.x * 4 + wv;
  float v = (l < 32) ? cand_v[(size_t)l * NBT + r] : INFINITY;
  int i = (l < 32) ? cand_i[(size_t)l * NBT + r] : 0x7fffffff;
  float mv[4];
  int mi[4];
#pragma unroll
  for (int k = 0; k < 4; ++k) {
    float bv = v;
    int bi = i;
#pragma unroll
    for (int msk = 1; msk < 64; msk <<= 1) {
      const float ov = __shfl_xor(bv, msk);
      const int oi = __shfl_xor(bi, msk);
      if (ov < bv || (ov == bv && oi < bi)) {
        bv = ov;
        bi = oi;
      }
    }
    mv[k] = bv;
    mi[k] = bi;
    if (i == bi) v = INFINITY;  // eliminate winner (indices unique)
  }
  const int b = r >> 12, t = r & (NT - 1);
  const float* xb = x + (size_t)b * ND * NT + t;
  float xv[8];
#pragma unroll
  for (int ii = 0; ii < 8; ++ii) xv[ii] = xb[(size_t)(l + 64 * ii) * NT];
  float dot[4];
#pragma unroll
  for (int k = 0; k < 4; ++k) {
    const float* e = emb + (size_t)mi[k] * ND;
    float d = 0.f;
#pragma unroll
    for (int ii = 0; ii < 8; ++ii) d += xv[ii] * e[l + 64 * ii];
    dot[k] = d;
  }
#pragma unroll
  for (int msk = 1; msk < 64; msk <<= 1) {
#pragma unroll
    for (int k = 0; k < 4; ++k) dot[k] += __shfl_xor(dot[k], msk);
  }
  __shared__ float wsum[4];
  if (l == 0) {
    float sb = INFINITY;
    int best = 0x7fffffff;
#pragma unroll
    for (int k = 0; k < 4; ++k) {
      const float s = enorm[mi[k]] - 2.f * dot[k];
      if (s < sb || (s == sb && mi[k] < best)) {
        sb = s;
        best = mi[k];
      }
    }
    idx_ws[r] = best;
    idxf[r] = (float)best;
    wsum[wv] = sb;  // loss term: enorm[best] - 2*dot_best
  }
  __syncthreads();
  if (tid == 0)
    lpart[blockIdx.x] = wsum[0] + wsum[1] + wsum[2] + wsum[3];
}

// ----------------------------------------------- gather (emb -> [B,D,T]) ---
__global__ __launch_bounds__(256) void gather_kernel(
    const float* __restrict__ emb, const int* __restrict__ idx_ws,
    float* __restrict__ vals_out) {
  __shared__ float tile[64][65];
  const int tid = threadIdx.x;
  const int bt0 = blockIdx.x * 64;
  const int d0 = blockIdx.y * 64;
  const int b = bt0 / NT;
  const int t0 = bt0 % NT;
  {
    const int dd4 = (tid & 15) * 4;
    const int ttb = tid >> 4;
#pragma unroll
    for (int p = 0; p < 4; ++p) {
      const int tt = ttb + p * 16;
      const int r = idx_ws[bt0 + tt];
      float4 v = *(const float4*)&emb[(size_t)r * ND + d0 + dd4];
      tile[tt][dd4 + 0] = v.x;
      tile[tt][dd4 + 1] = v.y;
      tile[tt][dd4 + 2] = v.z;
      tile[tt][dd4 + 3] = v.w;
    }
  }
  __syncthreads();
  {
    const int tt4 = (tid & 15) * 4;
    const int ddb = tid >> 4;
#pragma unroll
    for (int p = 0; p < 4; ++p) {
      const int dd = ddb + p * 16;
      float4 v;
      v.x = tile[tt4 + 0][dd];
      v.y = tile[tt4 + 1][dd];
      v.z = tile[tt4 + 2][dd];
      v.w = tile[tt4 + 3][dd];
      const size_t o = (size_t)b * ND * NT + (size_t)(d0 + dd) * NT + t0 + tt4;
      *(float4*)&vals_out[o] = v;
    }
  }
}

// ----------------------------------------------------------------- loss ----
__global__ void loss_kernel(const float* __restrict__ partials, int n,
                            float* __restrict__ out) {
  float s = 0.f;
  for (int i = threadIdx.x; i < n; i += 256) s += partials[i];
#pragma unroll
  for (int m = 32; m; m >>= 1) s += __shfl_xor(s, m);
  __shared__ float wsum[4];
  if ((threadIdx.x & 63) == 0) wsum[threadIdx.x >> 6] = s;
  __syncthreads();
  if (threadIdx.x == 0)
    out[0] = 2.0f * (wsum[0] + wsum[1] + wsum[2] + wsum[3]) /
             (float)((size_t)NB * ND * NT);
}

// --------------------------------------------------------------- launch ----
extern "C" void kernel_launch(void* const* d_in, const int* in_sizes, int n_in,
                              void* d_out, int out_size, void* d_ws,
                              size_t ws_size, hipStream_t stream) {
  const float* x = (const float*)d_in[0];
  const float* emb = (const float*)d_in[1];
  float* out = (float*)d_out;
  float* vals_out = out;                         // [B, D, T]
  float* idxf_out = out + (size_t)NB * ND * NT;  // [B, T] as float
  float* loss_out = idxf_out + NBT;              // scalar

  u16* xh = (u16*)d_ws;                            // NBT*ND
  u16* eh2 = xh + (size_t)NBT * ND;                // NK*ND
  float* enorm = (float*)(eh2 + (size_t)NK * ND);  // NK
  float* cand_v = enorm + NK;                      // CT*2*NBT
  int* cand_i = (int*)(cand_v + (size_t)CT * 2 * NBT);
  int* idx_ws = cand_i + (size_t)CT * 2 * NBT;  // NBT
  float* partials = (float*)(idx_ws + NBT);     // 2048 (x^2) + 4096 (rescore)

  conv_e_kernel<<<NK / 4, 256, 0, stream>>>(emb, eh2, enorm);
  conv_x_kernel<<<dim3(NBT / 64, ND / 64), 256, 0, stream>>>(x, xh, partials);
  argmin_gemm_kernel<<<2048, 512, 0, stream>>>(xh, eh2, enorm, cand_v,
                                               cand_i);
  combine_rescore_kernel<<<NBT / 4, 256, 0, stream>>>(
      cand_v, cand_i, x, emb, enorm, idx_ws, idxf_out, partials + 2048);
  gather_kernel<<<dim3(NBT / 64, ND / 64), 256, 0, stream>>>(emb, idx_ws,
                                                             vals_out);
  loss_kernel<<<1, 256, 0, stream>>>(partials, 2048 + 4096, loss_out);
}

// Round 18
// 206.846 us; speedup vs baseline: 1.2652x; 1.0016x over previous
//
#include <hip/hip_runtime.h>
#include <cstddef>
#include <cstdint>

#define NB 4
#define ND 512
#define NT 4096
#define NK 4096
#define NBT (NB * NT)
#define BKR 32         // real-k chunk
#define NCH (ND / BKR) // 16 chunks
#define CT (NK / 256)  // 16 col-blocks

typedef __attribute__((ext_vector_type(4))) float f32x4;
typedef __attribute__((ext_vector_type(8))) short short8;
typedef __attribute__((ext_vector_type(8))) unsigned short u16x8;
typedef unsigned short u16;

__device__ inline u16 f2bf_rn(float f) {
  unsigned u = __float_as_uint(f);
  return (u16)((u + 0x7FFFu + ((u >> 16) & 1u)) >> 16);
}
__device__ inline float bf2f(u16 h) {
  return __uint_as_float(((unsigned)h) << 16);
}
__device__ inline void gload16(void* lds_p, const void* g) {
  __builtin_amdgcn_global_load_lds(
      (const __attribute__((address_space(1))) unsigned int*)g,
      (__attribute__((address_space(3))) unsigned int*)lds_p, 16, 0, 0);
}

// ---------------------------------------------------- e conversion + norm --
__global__ void conv_e_kernel(const float* __restrict__ emb,
                              u16* __restrict__ eh2,
                              float* __restrict__ enorm) {
  int row = blockIdx.x * 4 + (threadIdx.x >> 6);
  int l = threadIdx.x & 63;
  const float* e = emb + (size_t)row * ND;
  float s = 0.f;
#pragma unroll
  for (int i = 0; i < ND / 64; ++i) {
    int idx = l + i * 64;
    float v = e[idx];
    s += v * v;
    eh2[(size_t)row * ND + idx] = f2bf_rn(2.f * v);
  }
#pragma unroll
  for (int m = 32; m; m >>= 1) s += __shfl_xor(s, m);
  if (l == 0) enorm[row] = s;
}

// ------------------- x conversion (+ transpose) + sum(x^2) partials --------
__global__ __launch_bounds__(256) void conv_x_kernel(const float* __restrict__ x,
                                                     u16* __restrict__ xh,
                                                     float* __restrict__ xsq) {
  __shared__ float tile[64][68];
  const int tid = threadIdx.x;
  const int bt0 = blockIdx.x * 64, d0 = blockIdx.y * 64;
  const int b = bt0 / NT, t0 = bt0 % NT;
  const float* xb = x + (size_t)b * ND * NT;
  float s2 = 0.f;
  {
    const int tt4 = (tid & 15) * 4, ddb = tid >> 4;
#pragma unroll
    for (int p = 0; p < 4; ++p) {
      const int dd = ddb + p * 16;
      float4 v = *(const float4*)&xb[(size_t)(d0 + dd) * NT + t0 + tt4];
      s2 += v.x * v.x + v.y * v.y + v.z * v.z + v.w * v.w;
      *(float4*)&tile[dd][tt4] = v;
    }
  }
  __syncthreads();
  {
    const int t_loc = tid >> 2, dg = tid & 3;
    u16 hs[16];
#pragma unroll
    for (int j = 0; j < 16; ++j) hs[j] = f2bf_rn(tile[dg * 16 + j][t_loc]);
    const size_t base = (size_t)(bt0 + t_loc) * ND + d0 + dg * 16;
    *(u16x8*)&xh[base] = *(const u16x8*)&hs[0];
    *(u16x8*)&xh[base + 8] = *(const u16x8*)&hs[8];
  }
#pragma unroll
  for (int m = 32; m; m >>= 1) s2 += __shfl_xor(s2, m);
  __shared__ float wsum[4];
  if ((tid & 63) == 0) wsum[tid >> 6] = s2;
  __syncthreads();
  if (tid == 0)
    xsq[blockIdx.y * gridDim.x + blockIdx.x] =
        wsum[0] + wsum[1] + wsum[2] + wsum[3];
}

// ------------- hi-only GEMM (128x256, 8 waves, 2 blocks/CU) + top-2 -------
// r17 structure + this round: fragment ds_reads issued FIRST (critical
// path), staging after; setprio(1) around the MFMA burst (2 independent
// blocks/CU = real phase diversity, T5's precondition); chunk loop fully
// unrolled so 3-periodic buffer addressing is compile-time constant.
__device__ __forceinline__ void stage_a(u16 (&la)[3][128][BKR], int bn, int tn,
                                        const u16* __restrict__ src,
                                        int rowbase, int w, int l) {
  if (tn >= NCH) return;
  const int kA = tn * BKR;
  const int rowL = w * 16 + (l >> 2);  // 8 waves x 16 rows = 128 rows
  const int gslot = (l & 3) ^ ((rowL >> 1) & 3);
  gload16(&la[bn][w * 16][0],
          &src[(size_t)(rowbase + rowL) * ND + kA + gslot * 8]);
}
__device__ __forceinline__ void stage_b(u16 (&lb)[3][256][BKR], int bn, int tn,
                                        const u16* __restrict__ src,
                                        int rowbase, int w, int l) {
  if (tn >= NCH) return;
  const int kA = tn * BKR;
#pragma unroll
  for (int i = 0; i < 2; ++i) {
    const int rowL = i * 128 + w * 16 + (l >> 2);
    const int gslot = (l & 3) ^ ((rowL >> 1) & 3);
    gload16(&lb[bn][i * 128 + w * 16][0],
            &src[(size_t)(rowbase + rowL) * ND + kA + gslot * 8]);
  }
}

__global__ __launch_bounds__(512, 4) void argmin_gemm_kernel(
    const u16* __restrict__ xh, const u16* __restrict__ eh2,
    const float* __restrict__ enorm, float* __restrict__ cand_v,
    int* __restrict__ cand_i) {
  __shared__ u16 lda[3][128][BKR];  // 24 KiB
  __shared__ u16 ldb[3][256][BKR];  // 48 KiB
  const int tid = threadIdx.x;
  const int w = tid >> 6, l = tid & 63;
  const int l15 = l & 15, l4 = l >> 4;
  const int wm = w >> 2, wn = w & 3;  // 2M x 4N waves, 64x64 each
  // XCD-aware bijective swizzle: nwg=2048, 256 blocks per XCD chunk.
  const int id = blockIdx.x;
  const int id_sw = (id & 7) * 256 + (id >> 3);
  const int bx = id_sw & 127, by = id_sw >> 7;
  const int bt0 = bx * 128, c0g = by * 256;

  f32x4 acc[4][2][2];  // [m][qn][n] = 64 regs
#pragma unroll
  for (int m = 0; m < 4; ++m)
#pragma unroll
    for (int qn = 0; qn < 2; ++qn)
#pragma unroll
      for (int n = 0; n < 2; ++n) acc[m][qn][n] = (f32x4)0.f;

#define SLOT(row) (((l4) ^ (((row) >> 1) & 3)) * 8)
#define DS_A(AF, CUR)                                                    \
  _Pragma("unroll") for (int m = 0; m < 4; ++m) {                        \
    const int row = wm * 64 + m * 16 + l15;                              \
    AF[m] = *(const short8*)&lda[CUR][row][SLOT(row)];                   \
  }
#define DS_B(BF, CUR)                                                    \
  _Pragma("unroll") for (int qn = 0; qn < 2; ++qn) {                     \
    _Pragma("unroll") for (int n = 0; n < 2; ++n) {                      \
      const int row = wn * 64 + qn * 32 + n * 16 + l15;                  \
      BF[qn * 2 + n] = *(const short8*)&ldb[CUR][row][SLOT(row)];        \
    }                                                                    \
  }
#define MM(AF, BF)                                                       \
  __builtin_amdgcn_s_setprio(1);                                         \
  _Pragma("unroll") for (int m = 0; m < 4; ++m) {                        \
    _Pragma("unroll") for (int qn = 0; qn < 2; ++qn) {                   \
      _Pragma("unroll") for (int n = 0; n < 2; ++n) {                    \
        acc[m][qn][n] = __builtin_amdgcn_mfma_f32_16x16x32_bf16(         \
            AF[m], BF[qn * 2 + n], acc[m][qn][n], 0, 0, 0);              \
      }                                                                  \
    }                                                                    \
  }                                                                      \
  __builtin_amdgcn_s_setprio(0);
#define BAR __builtin_amdgcn_s_barrier()
#define SB0 __builtin_amdgcn_sched_barrier(0)
#define VMC(N) asm volatile("s_waitcnt vmcnt(" #N ")" ::: "memory")

  // prologue: stage c0->buf0, c1->buf1 (6 loads); drain c0; Q=[c1:3].
  stage_a(lda, 0, 0, xh, bt0, w, l);
  stage_b(ldb, 0, 0, eh2, c0g, w, l);
  stage_a(lda, 1, 1, xh, bt0, w, l);
  stage_b(ldb, 1, 1, eh2, c0g, w, l);
  VMC(3);
  BAR;
  SB0;

#pragma unroll
  for (int t = 0; t < NCH; ++t) {
    const int cur = t % 3;
    const int b2 = (t + 2) % 3;
    // fragment reads FIRST (critical path: MFMAs wait on these)
    short8 aH[4], bH[4];
    DS_A(aH, cur);
    DS_B(bH, cur);
    // then stage chunk t+2 (VMEM pipe, non-blocking)
    stage_a(lda, b2, t + 2, xh, bt0, w, l);
    stage_b(ldb, b2, t + 2, eh2, c0g, w, l);
    MM(aH, bH);
    if (t < NCH - 2) {
      VMC(3);  // drain c(t+1); c(t+2) keeps a full chunk of slack
    } else {
      VMC(0);
    }
    BAR;  // all waves' reads of cur done; c(t+1) landed everywhere
    SB0;
  }
#undef SLOT
#undef DS_A
#undef DS_B
#undef MM
#undef VMC

  // ---- epilogue: per-row TOP-2 over this block's 256 cols ----
  __syncthreads();  // LDS reuse below
  float en[2][2];
#pragma unroll
  for (int qn = 0; qn < 2; ++qn)
#pragma unroll
    for (int n = 0; n < 2; ++n)
      en[qn][n] = enorm[c0g + wn * 64 + qn * 32 + n * 16 + l15];

  float* cvs2 = (float*)&lda[0][0][0];     // [4][128][2]
  int* cis2 = (int*)(cvs2 + 4 * 128 * 2);  // [4][128][2]

#pragma unroll
  for (int m = 0; m < 4; ++m) {
#pragma unroll
    for (int q = 0; q < 4; ++q) {
      float v1 = INFINITY, v2 = INFINITY;
      int i1 = 0, i2 = 0;
#pragma unroll
      for (int qn = 0; qn < 2; ++qn)  // ascending col order
#pragma unroll
        for (int n = 0; n < 2; ++n) {
          const float s = en[qn][n] - acc[m][qn][n][q];
          const int c = c0g + wn * 64 + qn * 32 + n * 16 + l15;
          if (s < v1) {
            v2 = v1; i2 = i1; v1 = s; i1 = c;
          } else if (s < v2) {
            v2 = s; i2 = c;
          }
        }
#pragma unroll
      for (int msk = 1; msk < 16; msk <<= 1) {
        const float ov1 = __shfl_xor(v1, msk);
        const int oi1 = __shfl_xor(i1, msk);
        const float ov2 = __shfl_xor(v2, msk);
        const int oi2 = __shfl_xor(i2, msk);
        const bool tk = ov1 < v1 || (ov1 == v1 && oi1 < i1);
        const float w2 = tk ? ov2 : v2;
        const int wj2 = tk ? oi2 : i2;
        const float lo1 = tk ? v1 : ov1;
        const int lj1 = tk ? i1 : oi1;
        v1 = tk ? ov1 : v1;
        i1 = tk ? oi1 : i1;
        const bool u = w2 < lo1 || (w2 == lo1 && wj2 < lj1);
        v2 = u ? w2 : lo1;
        i2 = u ? wj2 : lj1;
      }
      if (l15 == 0) {
        const int row = wm * 64 + m * 16 + l4 * 4 + q;
        cvs2[(wn * 128 + row) * 2 + 0] = v1;
        cis2[(wn * 128 + row) * 2 + 0] = i1;
        cvs2[(wn * 128 + row) * 2 + 1] = v2;
        cis2[(wn * 128 + row) * 2 + 1] = i2;
      }
    }
  }
  __syncthreads();
  if (tid < 128) {
    float v1 = INFINITY, v2 = INFINITY;
    int i1 = 0, i2 = 0;
#pragma unroll
    for (int g = 0; g < 4; ++g)
#pragma unroll
      for (int s = 0; s < 2; ++s) {
        const float v = cvs2[(g * 128 + tid) * 2 + s];
        const int i = cis2[(g * 128 + tid) * 2 + s];
        if (v < v1 || (v == v1 && i < i1)) {
          v2 = v1; i2 = i1; v1 = v; i1 = i;
        } else if (v < v2 || (v == v2 && i < i2)) {
          v2 = v; i2 = i;
        }
      }
    cand_v[(size_t)(by * 2 + 0) * NBT + bt0 + tid] = v1;
    cand_i[(size_t)(by * 2 + 0) * NBT + bt0 + tid] = i1;
    cand_v[(size_t)(by * 2 + 1) * NBT + bt0 + tid] = v2;
    cand_i[(size_t)(by * 2 + 1) * NBT + bt0 + tid] = i2;
  }
#undef BAR
#undef SB0
}

// -------- wave-per-row combine + exact fp32 top-4 rescore + loss partial ---
__global__ __launch_bounds__(256) void combine_rescore_kernel(
    const float* __restrict__ cand_v, const int* __restrict__ cand_i,
    const float* __restrict__ x, const float* __restrict__ emb,
    const float* __restrict__ enorm, int* __restrict__ idx_ws,
    float* __restrict__ idxf, float* __restrict__ lpart) {
  const int tid = threadIdx.x;
  const int wv = tid >> 6, l = tid & 63;
  const int r = blockIdx.x * 4 + wv;
  float v = (l < 32) ? cand_v[(size_t)l * NBT + r] : INFINITY;
  int i = (l < 32) ? cand_i[(size_t)l * NBT + r] : 0x7fffffff;
  float mv[4];
  int mi[4];
#pragma unroll
  for (int k = 0; k < 4; ++k) {
    float bv = v;
    int bi = i;
#pragma unroll
    for (int msk = 1; msk < 64; msk <<= 1) {
      const float ov = __shfl_xor(bv, msk);
      const int oi = __shfl_xor(bi, msk);
      if (ov < bv || (ov == bv && oi < bi)) {
        bv = ov;
        bi = oi;
      }
    }
    mv[k] = bv;
    mi[k] = bi;
    if (i == bi) v = INFINITY;  // eliminate winner (indices unique)
  }
  const int b = r >> 12, t = r & (NT - 1);
  const float* xb = x + (size_t)b * ND * NT + t;
  float xv[8];
#pragma unroll
  for (int ii = 0; ii < 8; ++ii) xv[ii] = xb[(size_t)(l + 64 * ii) * NT];
  float dot[4];
#pragma unroll
  for (int k = 0; k < 4; ++k) {
    const float* e = emb + (size_t)mi[k] * ND;
    float d = 0.f;
#pragma unroll
    for (int ii = 0; ii < 8; ++ii) d += xv[ii] * e[l + 64 * ii];
    dot[k] = d;
  }
#pragma unroll
  for (int msk = 1; msk < 64; msk <<= 1) {
#pragma unroll
    for (int k = 0; k < 4; ++k) dot[k] += __shfl_xor(dot[k], msk);
  }
  __shared__ float wsum[4];
  if (l == 0) {
    float sb = INFINITY;
    int best = 0x7fffffff;
#pragma unroll
    for (int k = 0; k < 4; ++k) {
      const float s = enorm[mi[k]] - 2.f * dot[k];
      if (s < sb || (s == sb && mi[k] < best)) {
        sb = s;
        best = mi[k];
      }
    }
    idx_ws[r] = best;
    idxf[r] = (float)best;
    wsum[wv] = sb;  // loss term: enorm[best] - 2*dot_best
  }
  __syncthreads();
  if (tid == 0)
    lpart[blockIdx.x] = wsum[0] + wsum[1] + wsum[2] + wsum[3];
}

// ----------------------------------------------- gather (emb -> [B,D,T]) ---
__global__ __launch_bounds__(256) void gather_kernel(
    const float* __restrict__ emb, const int* __restrict__ idx_ws,
    float* __restrict__ vals_out) {
  __shared__ float tile[64][65];
  const int tid = threadIdx.x;
  const int bt0 = blockIdx.x * 64;
  const int d0 = blockIdx.y * 64;
  const int b = bt0 / NT;
  const int t0 = bt0 % NT;
  {
    const int dd4 = (tid & 15) * 4;
    const int ttb = tid >> 4;
#pragma unroll
    for (int p = 0; p < 4; ++p) {
      const int tt = ttb + p * 16;
      const int r = idx_ws[bt0 + tt];
      float4 v = *(const float4*)&emb[(size_t)r * ND + d0 + dd4];
      tile[tt][dd4 + 0] = v.x;
      tile[tt][dd4 + 1] = v.y;
      tile[tt][dd4 + 2] = v.z;
      tile[tt][dd4 + 3] = v.w;
    }
  }
  __syncthreads();
  {
    const int tt4 = (tid & 15) * 4;
    const int ddb = tid >> 4;
#pragma unroll
    for (int p = 0; p < 4; ++p) {
      const int dd = ddb + p * 16;
      float4 v;
      v.x = tile[tt4 + 0][dd];
      v.y = tile[tt4 + 1][dd];
      v.z = tile[tt4 + 2][dd];
      v.w = tile[tt4 + 3][dd];
      const size_t o = (size_t)b * ND * NT + (size_t)(d0 + dd) * NT + t0 + tt4;
      *(float4*)&vals_out[o] = v;
    }
  }
}

// ----------------------------------------------------------------- loss ----
__global__ void loss_kernel(const float* __restrict__ partials, int n,
                            float* __restrict__ out) {
  float s = 0.f;
  for (int i = threadIdx.x; i < n; i += 256) s += partials[i];
#pragma unroll
  for (int m = 32; m; m >>= 1) s += __shfl_xor(s, m);
  __shared__ float wsum[4];
  if ((threadIdx.x & 63) == 0) wsum[threadIdx.x >> 6] = s;
  __syncthreads();
  if (threadIdx.x == 0)
    out[0] = 2.0f * (wsum[0] + wsum[1] + wsum[2] + wsum[3]) /
             (float)((size_t)NB * ND * NT);
}

// --------------------------------------------------------------- launch ----
extern "C" void kernel_launch(void* const* d_in, const int* in_sizes, int n_in,
                              void* d_out, int out_size, void* d_ws,
                              size_t ws_size, hipStream_t stream) {
  const float* x = (const float*)d_in[0];
  const float* emb = (const float*)d_in[1];
  float* out = (float*)d_out;
  float* vals_out = out;                         // [B, D, T]
  float* idxf_out = out + (size_t)NB * ND * NT;  // [B, T] as float
  float* loss_out = idxf_out + NBT;              // scalar

  u16* xh = (u16*)d_ws;                            // NBT*ND
  u16* eh2 = xh + (size_t)NBT * ND;                // NK*ND
  float* enorm = (float*)(eh2 + (size_t)NK * ND);  // NK
  float* cand_v = enorm + NK;                      // CT*2*NBT
  int* cand_i = (int*)(cand_v + (size_t)CT * 2 * NBT);
  int* idx_ws = cand_i + (size_t)CT * 2 * NBT;  // NBT
  float* partials = (float*)(idx_ws + NBT);     // 2048 (x^2) + 4096 (rescore)

  conv_e_kernel<<<NK / 4, 256, 0, stream>>>(emb, eh2, enorm);
  conv_x_kernel<<<dim3(NBT / 64, ND / 64), 256, 0, stream>>>(x, xh, partials);
  argmin_gemm_kernel<<<2048, 512, 0, stream>>>(xh, eh2, enorm, cand_v,
                                               cand_i);
  combine_rescore_kernel<<<NBT / 4, 256, 0, stream>>>(
      cand_v, cand_i, x, emb, enorm, idx_ws, idxf_out, partials + 2048);
  gather_kernel<<<dim3(NBT / 64, ND / 64), 256, 0, stream>>>(emb, idx_ws,
                                                             vals_out);
  loss_kernel<<<1, 256, 0, stream>>>(partials, 2048 + 4096, loss_out);
}

// Round 19
// 181.593 us; speedup vs baseline: 1.4411x; 1.1391x over previous
//
#include <hip/hip_runtime.h>
#include <cstddef>
#include <cstdint>

#define NB 4
#define ND 512
#define NT 4096
#define NK 4096
#define NBT (NB * NT)
#define BKR 32         // real-k chunk
#define NCH (ND / BKR) // 16 chunks
#define CT (NK / 256)  // 16 col-blocks

typedef __attribute__((ext_vector_type(4))) float f32x4;
typedef __attribute__((ext_vector_type(8))) short short8;
typedef __attribute__((ext_vector_type(8))) unsigned short u16x8;
typedef unsigned short u16;

__device__ inline u16 f2bf_rn(float f) {
  unsigned u = __float_as_uint(f);
  return (u16)((u + 0x7FFFu + ((u >> 16) & 1u)) >> 16);
}
__device__ inline void gload16(void* lds_p, const void* g) {
  __builtin_amdgcn_global_load_lds(
      (const __attribute__((address_space(1))) unsigned int*)g,
      (__attribute__((address_space(3))) unsigned int*)lds_p, 16, 0, 0);
}
// monotone fp32 -> u32 (order-preserving, incl. negatives)
__device__ inline unsigned mono(float f) {
  unsigned u = __float_as_uint(f);
  return u ^ ((unsigned)((int)u >> 31) | 0x80000000u);
}

// ---------------------------------------------------- e conversion + norm --
__global__ void conv_e_kernel(const float* __restrict__ emb,
                              u16* __restrict__ eh2,
                              float* __restrict__ enorm) {
  int row = blockIdx.x * 4 + (threadIdx.x >> 6);
  int l = threadIdx.x & 63;
  const float* e = emb + (size_t)row * ND;
  float s = 0.f;
#pragma unroll
  for (int i = 0; i < ND / 64; ++i) {
    int idx = l + i * 64;
    float v = e[idx];
    s += v * v;
    eh2[(size_t)row * ND + idx] = f2bf_rn(2.f * v);
  }
#pragma unroll
  for (int m = 32; m; m >>= 1) s += __shfl_xor(s, m);
  if (l == 0) enorm[row] = s;
}

// ------------------- x conversion (+ transpose) + sum(x^2) partials --------
__global__ __launch_bounds__(256) void conv_x_kernel(const float* __restrict__ x,
                                                     u16* __restrict__ xh,
                                                     float* __restrict__ xsq) {
  __shared__ float tile[64][68];
  const int tid = threadIdx.x;
  const int bt0 = blockIdx.x * 64, d0 = blockIdx.y * 64;
  const int b = bt0 / NT, t0 = bt0 % NT;
  const float* xb = x + (size_t)b * ND * NT;
  float s2 = 0.f;
  {
    const int tt4 = (tid & 15) * 4, ddb = tid >> 4;
#pragma unroll
    for (int p = 0; p < 4; ++p) {
      const int dd = ddb + p * 16;
      float4 v = *(const float4*)&xb[(size_t)(d0 + dd) * NT + t0 + tt4];
      s2 += v.x * v.x + v.y * v.y + v.z * v.z + v.w * v.w;
      *(float4*)&tile[dd][tt4] = v;
    }
  }
  __syncthreads();
  {
    const int t_loc = tid >> 2, dg = tid & 3;
    u16 hs[16];
#pragma unroll
    for (int j = 0; j < 16; ++j) hs[j] = f2bf_rn(tile[dg * 16 + j][t_loc]);
    const size_t base = (size_t)(bt0 + t_loc) * ND + d0 + dg * 16;
    *(u16x8*)&xh[base] = *(const u16x8*)&hs[0];
    *(u16x8*)&xh[base + 8] = *(const u16x8*)&hs[8];
  }
#pragma unroll
  for (int m = 32; m; m >>= 1) s2 += __shfl_xor(s2, m);
  __shared__ float wsum[4];
  if ((tid & 63) == 0) wsum[tid >> 6] = s2;
  __syncthreads();
  if (tid == 0)
    xsq[blockIdx.y * gridDim.x + blockIdx.x] =
        wsum[0] + wsum[1] + wsum[2] + wsum[3];
}

// ------------- hi-only GEMM (128x256, 8 waves, 2 blocks/CU) + top-2 -------
// r18 main loop unchanged. NEW packed-key epilogue: approx score -> single
// monotone u32 key (20-bit value | 12-bit global col; cols distinct => keys
// unique). Top-2 butterfly carries 1 u32/candidate: 2 shuffles/pass (was 4),
// ~5 VALU/merge (was ~14) -> epilogue LDS-pipe cost ~halved. Cross-wave
// merge via 4.6 KB kbuf + 128-thread scan. Candidates stored as keys.
__device__ __forceinline__ void stage_a(u16 (&la)[3][128][BKR], int bn, int tn,
                                        const u16* __restrict__ src,
                                        int rowbase, int w, int l) {
  if (tn >= NCH) return;
  const int kA = tn * BKR;
  const int rowL = w * 16 + (l >> 2);
  const int gslot = (l & 3) ^ ((rowL >> 1) & 3);
  gload16(&la[bn][w * 16][0],
          &src[(size_t)(rowbase + rowL) * ND + kA + gslot * 8]);
}
__device__ __forceinline__ void stage_b(u16 (&lb)[3][256][BKR], int bn, int tn,
                                        const u16* __restrict__ src,
                                        int rowbase, int w, int l) {
  if (tn >= NCH) return;
  const int kA = tn * BKR;
#pragma unroll
  for (int i = 0; i < 2; ++i) {
    const int rowL = i * 128 + w * 16 + (l >> 2);
    const int gslot = (l & 3) ^ ((rowL >> 1) & 3);
    gload16(&lb[bn][i * 128 + w * 16][0],
            &src[(size_t)(rowbase + rowL) * ND + kA + gslot * 8]);
  }
}

__global__ __launch_bounds__(512, 4) void argmin_gemm_kernel(
    const u16* __restrict__ xh, const u16* __restrict__ eh2,
    const float* __restrict__ enorm, unsigned* __restrict__ cand_k) {
  __shared__ u16 lda[3][128][BKR];  // 24 KiB
  __shared__ u16 ldb[3][256][BKR];  // 48 KiB
  const int tid = threadIdx.x;
  const int w = tid >> 6, l = tid & 63;
  const int l15 = l & 15, l4 = l >> 4;
  const int wm = w >> 2, wn = w & 3;  // 2M x 4N waves, 64x64 each
  // XCD-aware bijective swizzle: nwg=2048, 256 blocks per XCD chunk.
  const int id = blockIdx.x;
  const int id_sw = (id & 7) * 256 + (id >> 3);
  const int bx = id_sw & 127, by = id_sw >> 7;
  const int bt0 = bx * 128, c0g = by * 256;

  f32x4 acc[4][2][2];  // [m][qn][n] = 64 regs
#pragma unroll
  for (int m = 0; m < 4; ++m)
#pragma unroll
    for (int qn = 0; qn < 2; ++qn)
#pragma unroll
      for (int n = 0; n < 2; ++n) acc[m][qn][n] = (f32x4)0.f;

#define SLOT(row) (((l4) ^ (((row) >> 1) & 3)) * 8)
#define DS_A(AF, CUR)                                                    \
  _Pragma("unroll") for (int m = 0; m < 4; ++m) {                        \
    const int row = wm * 64 + m * 16 + l15;                              \
    AF[m] = *(const short8*)&lda[CUR][row][SLOT(row)];                   \
  }
#define DS_B(BF, CUR)                                                    \
  _Pragma("unroll") for (int qn = 0; qn < 2; ++qn) {                     \
    _Pragma("unroll") for (int n = 0; n < 2; ++n) {                      \
      const int row = wn * 64 + qn * 32 + n * 16 + l15;                  \
      BF[qn * 2 + n] = *(const short8*)&ldb[CUR][row][SLOT(row)];        \
    }                                                                    \
  }
#define MM(AF, BF)                                                       \
  __builtin_amdgcn_s_setprio(1);                                         \
  _Pragma("unroll") for (int m = 0; m < 4; ++m) {                        \
    _Pragma("unroll") for (int qn = 0; qn < 2; ++qn) {                   \
      _Pragma("unroll") for (int n = 0; n < 2; ++n) {                    \
        acc[m][qn][n] = __builtin_amdgcn_mfma_f32_16x16x32_bf16(         \
            AF[m], BF[qn * 2 + n], acc[m][qn][n], 0, 0, 0);              \
      }                                                                  \
    }                                                                    \
  }                                                                      \
  __builtin_amdgcn_s_setprio(0);
#define BAR __builtin_amdgcn_s_barrier()
#define SB0 __builtin_amdgcn_sched_barrier(0)
#define VMC(N) asm volatile("s_waitcnt vmcnt(" #N ")" ::: "memory")

  // prologue: stage c0->buf0, c1->buf1 (6 loads); drain c0; Q=[c1:3].
  stage_a(lda, 0, 0, xh, bt0, w, l);
  stage_b(ldb, 0, 0, eh2, c0g, w, l);
  stage_a(lda, 1, 1, xh, bt0, w, l);
  stage_b(ldb, 1, 1, eh2, c0g, w, l);
  VMC(3);
  BAR;
  SB0;

#pragma unroll
  for (int t = 0; t < NCH; ++t) {
    const int cur = t % 3;
    const int b2 = (t + 2) % 3;
    short8 aH[4], bH[4];
    DS_A(aH, cur);
    DS_B(bH, cur);
    stage_a(lda, b2, t + 2, xh, bt0, w, l);
    stage_b(ldb, b2, t + 2, eh2, c0g, w, l);
    MM(aH, bH);
    if (t < NCH - 2) {
      VMC(3);
    } else {
      VMC(0);
    }
    BAR;
    SB0;
  }
#undef SLOT
#undef DS_A
#undef DS_B
#undef MM
#undef VMC

  // ---- epilogue: per-row TOP-2 keys over this block's 256 cols ----
  __syncthreads();  // LDS reuse below
  unsigned* kbuf = (unsigned*)&lda[0][0][0];  // [128][9] padded, 4.6 KB
  float en[2][2];
#pragma unroll
  for (int qn = 0; qn < 2; ++qn)
#pragma unroll
    for (int n = 0; n < 2; ++n)
      en[qn][n] = enorm[c0g + wn * 64 + qn * 32 + n * 16 + l15];

#pragma unroll
  for (int m = 0; m < 4; ++m) {
#pragma unroll
    for (int q = 0; q < 4; ++q) {
      unsigned k1 = 0xFFFFFFFFu, k2 = 0xFFFFFFFFu;
#pragma unroll
      for (int qn = 0; qn < 2; ++qn)
#pragma unroll
        for (int n = 0; n < 2; ++n) {
          const float s = en[qn][n] - acc[m][qn][n][q];
          const int col = c0g + wn * 64 + qn * 32 + n * 16 + l15;
          const unsigned key = (mono(s) & 0xFFFFF000u) | (unsigned)col;
          const unsigned lo = key < k1 ? key : k1;
          const unsigned hi = key < k1 ? k1 : key;
          k1 = lo;
          k2 = hi < k2 ? hi : k2;
        }
      // butterfly top-2 merge across the 16 col-lanes: 2 shuffles/pass
#pragma unroll
      for (int msk = 1; msk < 16; msk <<= 1) {
        const unsigned o1 = (unsigned)__shfl_xor((int)k1, msk);
        const unsigned o2 = (unsigned)__shfl_xor((int)k2, msk);
        const unsigned n1 = k1 < o1 ? k1 : o1;
        const unsigned x1 = k1 < o1 ? o1 : k1;  // max of firsts
        const unsigned c2 = k1 < o1 ? k2 : o2;  // winner's second
        k1 = n1;
        k2 = x1 < c2 ? x1 : c2;
      }
      if (l15 == 0) {
        const int row = wm * 64 + m * 16 + l4 * 4 + q;
        kbuf[row * 9 + wn * 2 + 0] = k1;
        kbuf[row * 9 + wn * 2 + 1] = k2;
      }
    }
  }
  __syncthreads();
  if (tid < 128) {
    unsigned k1 = 0xFFFFFFFFu, k2 = 0xFFFFFFFFu;
#pragma unroll
    for (int g = 0; g < 8; ++g) {
      const unsigned key = kbuf[tid * 9 + g];
      const unsigned lo = key < k1 ? key : k1;
      const unsigned hi = key < k1 ? k1 : key;
      k1 = lo;
      k2 = hi < k2 ? hi : k2;
    }
    cand_k[(size_t)(by * 2 + 0) * NBT + bt0 + tid] = k1;
    cand_k[(size_t)(by * 2 + 1) * NBT + bt0 + tid] = k2;
  }
#undef BAR
#undef SB0
}

// ------ wave-per-row combine (keys) + exact fp32 top-4 rescore + loss ------
__global__ __launch_bounds__(256) void combine_rescore_kernel(
    const unsigned* __restrict__ cand_k, const float* __restrict__ x,
    const float* __restrict__ emb, const float* __restrict__ enorm,
    int* __restrict__ idx_ws, float* __restrict__ idxf,
    float* __restrict__ lpart) {
  const int tid = threadIdx.x;
  const int wv = tid >> 6, l = tid & 63;
  const int r = blockIdx.x * 4 + wv;
  // approx top-4 of 32 candidate keys (unique) via 4 umin butterflies
  unsigned k = (l < 32) ? cand_k[(size_t)l * NBT + r] : 0xFFFFFFFFu;
  int mi[4];
#pragma unroll
  for (int kk = 0; kk < 4; ++kk) {
    unsigned bk = k;
#pragma unroll
    for (int msk = 1; msk < 64; msk <<= 1) {
      const unsigned ok = (unsigned)__shfl_xor((int)bk, msk);
      bk = ok < bk ? ok : bk;
    }
    mi[kk] = (int)(bk & 0xFFFu);
    if (k == bk) k = 0xFFFFFFFFu;  // keys unique -> clean elimination
  }
  // exact fp32 dots: x loaded once per lane, 4 coalesced e-rows
  const int b = r >> 12, t = r & (NT - 1);
  const float* xb = x + (size_t)b * ND * NT + t;
  float xv[8];
#pragma unroll
  for (int ii = 0; ii < 8; ++ii) xv[ii] = xb[(size_t)(l + 64 * ii) * NT];
  float dot[4];
#pragma unroll
  for (int kk = 0; kk < 4; ++kk) {
    const float* e = emb + (size_t)mi[kk] * ND;
    float d = 0.f;
#pragma unroll
    for (int ii = 0; ii < 8; ++ii) d += xv[ii] * e[l + 64 * ii];
    dot[kk] = d;
  }
#pragma unroll
  for (int msk = 1; msk < 64; msk <<= 1) {
#pragma unroll
    for (int kk = 0; kk < 4; ++kk) dot[kk] += __shfl_xor(dot[kk], msk);
  }
  __shared__ float wsum[4];
  if (l == 0) {
    float sb = INFINITY;
    int best = 0x7fffffff;
#pragma unroll
    for (int kk = 0; kk < 4; ++kk) {
      const float s = enorm[mi[kk]] - 2.f * dot[kk];
      if (s < sb || (s == sb && mi[kk] < best)) {
        sb = s;
        best = mi[kk];
      }
    }
    idx_ws[r] = best;
    idxf[r] = (float)best;
    wsum[wv] = sb;  // loss term: enorm[best] - 2*dot_best
  }
  __syncthreads();
  if (tid == 0)
    lpart[blockIdx.x] = wsum[0] + wsum[1] + wsum[2] + wsum[3];
}

// ----------------------------------------------- gather (emb -> [B,D,T]) ---
__global__ __launch_bounds__(256) void gather_kernel(
    const float* __restrict__ emb, const int* __restrict__ idx_ws,
    float* __restrict__ vals_out) {
  __shared__ float tile[64][65];
  const int tid = threadIdx.x;
  const int bt0 = blockIdx.x * 64;
  const int d0 = blockIdx.y * 64;
  const int b = bt0 / NT;
  const int t0 = bt0 % NT;
  {
    const int dd4 = (tid & 15) * 4;
    const int ttb = tid >> 4;
#pragma unroll
    for (int p = 0; p < 4; ++p) {
      const int tt = ttb + p * 16;
      const int r = idx_ws[bt0 + tt];
      float4 v = *(const float4*)&emb[(size_t)r * ND + d0 + dd4];
      tile[tt][dd4 + 0] = v.x;
      tile[tt][dd4 + 1] = v.y;
      tile[tt][dd4 + 2] = v.z;
      tile[tt][dd4 + 3] = v.w;
    }
  }
  __syncthreads();
  {
    const int tt4 = (tid & 15) * 4;
    const int ddb = tid >> 4;
#pragma unroll
    for (int p = 0; p < 4; ++p) {
      const int dd = ddb + p * 16;
      float4 v;
      v.x = tile[tt4 + 0][dd];
      v.y = tile[tt4 + 1][dd];
      v.z = tile[tt4 + 2][dd];
      v.w = tile[tt4 + 3][dd];
      const size_t o = (size_t)b * ND * NT + (size_t)(d0 + dd) * NT + t0 + tt4;
      *(float4*)&vals_out[o] = v;
    }
  }
}

// ----------------------------------------------------------------- loss ----
__global__ void loss_kernel(const float* __restrict__ partials, int n,
                            float* __restrict__ out) {
  float s = 0.f;
  for (int i = threadIdx.x; i < n; i += 256) s += partials[i];
#pragma unroll
  for (int m = 32; m; m >>= 1) s += __shfl_xor(s, m);
  __shared__ float wsum[4];
  if ((threadIdx.x & 63) == 0) wsum[threadIdx.x >> 6] = s;
  __syncthreads();
  if (threadIdx.x == 0)
    out[0] = 2.0f * (wsum[0] + wsum[1] + wsum[2] + wsum[3]) /
             (float)((size_t)NB * ND * NT);
}

// --------------------------------------------------------------- launch ----
extern "C" void kernel_launch(void* const* d_in, const int* in_sizes, int n_in,
                              void* d_out, int out_size, void* d_ws,
                              size_t ws_size, hipStream_t stream) {
  const float* x = (const float*)d_in[0];
  const float* emb = (const float*)d_in[1];
  float* out = (float*)d_out;
  float* vals_out = out;                         // [B, D, T]
  float* idxf_out = out + (size_t)NB * ND * NT;  // [B, T] as float
  float* loss_out = idxf_out + NBT;              // scalar

  u16* xh = (u16*)d_ws;                            // NBT*ND
  u16* eh2 = xh + (size_t)NBT * ND;                // NK*ND
  float* enorm = (float*)(eh2 + (size_t)NK * ND);  // NK
  unsigned* cand_k = (unsigned*)(enorm + NK);      // CT*2*NBT
  int* idx_ws = (int*)(cand_k + (size_t)CT * 2 * NBT);  // NBT
  float* partials = (float*)(idx_ws + NBT);  // 2048 (x^2) + 4096 (rescore)

  conv_e_kernel<<<NK / 4, 256, 0, stream>>>(emb, eh2, enorm);
  conv_x_kernel<<<dim3(NBT / 64, ND / 64), 256, 0, stream>>>(x, xh, partials);
  argmin_gemm_kernel<<<2048, 512, 0, stream>>>(xh, eh2, enorm, cand_k);
  combine_rescore_kernel<<<NBT / 4, 256, 0, stream>>>(
      cand_k, x, emb, enorm, idx_ws, idxf_out, partials + 2048);
  gather_kernel<<<dim3(NBT / 64, ND / 64), 256, 0, stream>>>(emb, idx_ws,
                                                             vals_out);
  loss_kernel<<<1, 256, 0, stream>>>(partials, 2048 + 4096, loss_out);
}